// Round 3
// baseline (190.388 us; speedup 1.0000x reference)
//
#include <hip/hip_runtime.h>

#define IN_CH 256
#define IMG_H 56
#define IMG_W 56

typedef float v4f __attribute__((ext_vector_type(4)));

// out[b,c]   = conv3x3(x[b,c],   w[2c])      + conv3x3(x[b,c^4], w[2(c^4)+1])
// out[b,c^4] = conv3x3(x[b,c^4], w[2(c^4)])  + conv3x3(x[b,c],   w[2c+1])
// One block per (pair p, batch b). Thread (s,i): rows 4s..4s+3, cols 4i..4i+3.
// 16-lane groups per row-strip so shfl neighbors stay in-strip; i in [0,14).
__global__ __launch_bounds__(256) void dwconv_butterfly(
    const float* __restrict__ x, const float* __restrict__ wgt,
    float* __restrict__ out)
{
    const int tid = threadIdx.x;
    const int s   = tid >> 4;          // row-strip 0..15 (active < 14)
    const int i   = tid & 15;          // col-quad  0..15 (active < 14)
    const bool active = (s < 14) && (i < 14);

    const int p  = blockIdx.x;         // 0..127
    const int b  = blockIdx.y;         // 0..31
    const int c0 = ((p >> 2) << 3) | (p & 3);   // bit2 == 0
    const int c1 = c0 ^ 4;

    const size_t chan = (size_t)IMG_H * IMG_W;
    const float* x0 = x + ((size_t)b * IN_CH + c0) * chan;
    const float* x1 = x + ((size_t)b * IN_CH + c1) * chan;
    float* o0 = out + ((size_t)b * IN_CH + c0) * chan;
    float* o1 = out + ((size_t)b * IN_CH + c1) * chan;

    // Weights: wave-uniform addresses -> scalar (SGPR) loads.
    float wa[9], wb[9], wc[9], wd[9];
    {
        const float* pa = wgt + (size_t)(2 * c0) * 9;
        const float* pb = wgt + (size_t)(2 * c1 + 1) * 9;
        const float* pc = wgt + (size_t)(2 * c1) * 9;
        const float* pd = wgt + (size_t)(2 * c0 + 1) * 9;
#pragma unroll
        for (int k = 0; k < 9; ++k) {
            wa[k] = pa[k]; wb[k] = pb[k]; wc[k] = pc[k]; wd[k] = pd[k];
        }
    }

    const int row0 = 4 * s - 1;        // first input row this thread needs
    const int col  = 4 * i;

    // ---- 12 independent vector loads: 6 input rows x 2 channels ----
    float4 v0[6], v1[6];
#pragma unroll
    for (int k = 0; k < 6; ++k) {
        const int  rr = row0 + k;
        const bool ok = active && (rr >= 0) && (rr < IMG_H);
        if (ok) {
            v0[k] = *(const float4*)(x0 + rr * IMG_W + col);
            v1[k] = *(const float4*)(x1 + rr * IMG_W + col);
        } else {
            v0[k] = make_float4(0.f, 0.f, 0.f, 0.f);
            v1[k] = make_float4(0.f, 0.f, 0.f, 0.f);
        }
    }

    // ---- halo columns from neighbor lanes (no LDS, no barrier) ----
    float l0[6], r0h[6], l1[6], r1h[6];
#pragma unroll
    for (int k = 0; k < 6; ++k) {
        const float a = __shfl_up(v0[k].w, 1);
        const float bb = __shfl_up(v1[k].w, 1);
        const float c = __shfl_down(v0[k].x, 1);
        const float d = __shfl_down(v1[k].x, 1);
        l0[k]  = (i == 0)  ? 0.f : a;
        l1[k]  = (i == 0)  ? 0.f : bb;
        r0h[k] = (i == 13) ? 0.f : c;
        r1h[k] = (i == 13) ? 0.f : d;
    }

    // ---- compute 4 output rows from registers ----
#pragma unroll
    for (int m = 0; m < 4; ++m) {
        float acc0[4] = {0.f, 0.f, 0.f, 0.f};
        float acc1[4] = {0.f, 0.f, 0.f, 0.f};
#pragma unroll
        for (int kh = 0; kh < 3; ++kh) {
            const int k = m + kh;      // input row index in the 6-row window
            const float e0[6] = {l0[k], v0[k].x, v0[k].y, v0[k].z, v0[k].w, r0h[k]};
            const float e1[6] = {l1[k], v1[k].x, v1[k].y, v1[k].z, v1[k].w, r1h[k]};
#pragma unroll
            for (int kw = 0; kw < 3; ++kw) {
                const float fa = wa[kh * 3 + kw], fb = wb[kh * 3 + kw];
                const float fc = wc[kh * 3 + kw], fd = wd[kh * 3 + kw];
#pragma unroll
                for (int q = 0; q < 4; ++q) {
                    acc0[q] += e0[q + kw] * fa + e1[q + kw] * fb;
                    acc1[q] += e1[q + kw] * fc + e0[q + kw] * fd;
                }
            }
        }
        if (active) {
            const int orow = 4 * s + m;
            v4f s0 = {acc0[0], acc0[1], acc0[2], acc0[3]};
            v4f s1 = {acc1[0], acc1[1], acc1[2], acc1[3]};
            __builtin_nontemporal_store(s0, (v4f*)(o0 + orow * IMG_W + col));
            __builtin_nontemporal_store(s1, (v4f*)(o1 + orow * IMG_W + col));
        }
    }
}

extern "C" void kernel_launch(void* const* d_in, const int* in_sizes, int n_in,
                              void* d_out, int out_size, void* d_ws, size_t ws_size,
                              hipStream_t stream) {
    const float* x = (const float*)d_in[0];   // (32, 256, 56, 56) fp32
    const float* w = (const float*)d_in[1];   // (512, 1, 3, 3)   fp32
    float* out = (float*)d_out;               // (32, 256, 56, 56) fp32

    dim3 grid(IN_CH / 2, 32);   // 128 channel-pairs x 32 batch
    dim3 block(256);
    dwconv_butterfly<<<grid, block, 0, stream>>>(x, w, out);
}